// Round 1
// baseline (193.638 us; speedup 1.0000x reference)
//
#include <hip/hip_runtime.h>
#include <hip/hip_bf16.h>

typedef _Float16 h8 __attribute__((ext_vector_type(8)));
typedef _Float16 h4 __attribute__((ext_vector_type(4)));
typedef float f4 __attribute__((ext_vector_type(4)));

#define S_LEN 2048
#define EMB 1024
#define NH 16
#define DH 64

__device__ __forceinline__ void async_copy16(const void* g, void* l) {
  __builtin_amdgcn_global_load_lds(
      (const __attribute__((address_space(1))) void*)g,
      (__attribute__((address_space(3))) void*)l, 16, 0, 0);
}

__device__ __forceinline__ f4 mfma16(h8 a, h8 b, f4 c) {
  return __builtin_amdgcn_mfma_f32_16x16x32_f16(a, b, c, 0, 0, 0);
}

// ---------------- conversions / transposes ----------------

__global__ void cvtx_kernel(const float* __restrict__ x, _Float16* __restrict__ xh) {
  const int i = blockIdx.x * 256 + threadIdx.x;      // *4 elements
  const float4 v = *(const float4*)&x[(long)i * 4];
  h4 o;
  o.x = (_Float16)v.x; o.y = (_Float16)v.y; o.z = (_Float16)v.z; o.w = (_Float16)v.w;
  *(h4*)&xh[(long)i * 4] = o;
}

// W[k][n] f32 -> Wt[n][k] f16, 7 weights selected by blockIdx.z
__global__ void twcvt_kernel(const float* w0, const float* w1, const float* w2,
                             const float* w3, const float* w4, const float* w5,
                             const float* w6, _Float16* __restrict__ outb) {
  const float* W = w0;
  switch (blockIdx.z) {
    case 1: W = w1; break; case 2: W = w2; break; case 3: W = w3; break;
    case 4: W = w4; break; case 5: W = w5; break; case 6: W = w6; break;
    default: break;
  }
  __shared__ float t[32][33];
  const int bk = blockIdx.x * 32, bn = blockIdx.y * 32;
  const int tx = threadIdx.x & 31, ty = threadIdx.x >> 5;   // 32 x 8
  #pragma unroll
  for (int i = 0; i < 4; ++i)
    t[ty + i * 8][tx] = W[(long)(bk + ty + i * 8) * 1024 + bn + tx];
  __syncthreads();
  _Float16* o = outb + (long)blockIdx.z * 1048576;
  #pragma unroll
  for (int i = 0; i < 4; ++i)
    o[(long)(bn + ty + i * 8) * 1024 + bk + tx] = (_Float16)t[tx][ty + i * 8];
}

// vg [2048][1024] f16 -> vgT [1024][2048] f16
__global__ void tvg_kernel(const _Float16* __restrict__ vg, _Float16* __restrict__ vgT) {
  __shared__ _Float16 t[32][33];
  const int bs = blockIdx.x * 32, be = blockIdx.y * 32;
  const int tx = threadIdx.x & 31, ty = threadIdx.x >> 5;
  #pragma unroll
  for (int i = 0; i < 4; ++i)
    t[ty + i * 8][tx] = vg[(long)(bs + ty + i * 8) * 1024 + be + tx];
  __syncthreads();
  #pragma unroll
  for (int i = 0; i < 4; ++i)
    vgT[(long)(be + ty + i * 8) * 2048 + bs + tx] = t[tx][ty + i * 8];
}

// ---------------- GEMM: C[M][N] = A[M][K] * Bt[N][K]^T ----------------
// 128x128 tile, BK=64, 4 waves, global_load_lds w/ source-swizzle, swizzled ds_read_b128

template <bool F32OUT, bool HAS_BIAS>
__global__ __launch_bounds__(256) void gemm_kernel(
    const _Float16* __restrict__ A, const _Float16* __restrict__ Bt,
    void* __restrict__ Cv, const float* __restrict__ bias,
    int M, int N, int K, long sA, long sB, long sC) {
  const _Float16* Ab = A + (long)blockIdx.z * sA;
  const _Float16* Bb = Bt + (long)blockIdx.z * sB;
  const int bm = blockIdx.x * 128, bn = blockIdx.y * 128;
  __shared__ alignas(16) _Float16 As[128 * 64];
  __shared__ alignas(16) _Float16 Bs[128 * 64];
  const int tid = threadIdx.x;
  const int w = tid >> 6, l = tid & 63;
  const int lo = l & 15, hi = l >> 4;
  const int wr = (w >> 1) * 64, wc = (w & 1) * 64;
  const int srow = l >> 3, ssp = l & 7;
  const int ssl = ssp ^ (srow & 7);   // source-swizzled logical k-seg

  const f4 zero = {0.f, 0.f, 0.f, 0.f};
  f4 acc[4][4];
  #pragma unroll
  for (int m = 0; m < 4; ++m)
    #pragma unroll
    for (int n = 0; n < 4; ++n) acc[m][n] = zero;

  for (int k0 = 0; k0 < K; k0 += 64) {
    #pragma unroll
    for (int i = 0; i < 4; ++i) {
      const int chunk = w + i * 4;   // 16 chunks of 8 rows x 64 f16
      async_copy16(&Ab[(long)(bm + chunk * 8 + srow) * K + k0 + ssl * 8], &As[chunk * 512]);
      async_copy16(&Bb[(long)(bn + chunk * 8 + srow) * K + k0 + ssl * 8], &Bs[chunk * 512]);
    }
    __syncthreads();
    #pragma unroll
    for (int kk = 0; kk < 2; ++kk) {
      h8 af[4], bf[4];
      #pragma unroll
      for (int m = 0; m < 4; ++m) {
        const int r = wr + m * 16 + lo;
        af[m] = *(const h8*)&As[r * 64 + (((kk * 4 + hi) ^ (r & 7)) * 8)];
      }
      #pragma unroll
      for (int n = 0; n < 4; ++n) {
        const int r = wc + n * 16 + lo;
        bf[n] = *(const h8*)&Bs[r * 64 + (((kk * 4 + hi) ^ (r & 7)) * 8)];
      }
      #pragma unroll
      for (int m = 0; m < 4; ++m)
        #pragma unroll
        for (int n = 0; n < 4; ++n)
          acc[m][n] = mfma16(af[m], bf[n], acc[m][n]);
    }
    __syncthreads();
  }

  #pragma unroll
  for (int m = 0; m < 4; ++m) {
    const int row0 = bm + wr + m * 16 + hi * 4;
    #pragma unroll
    for (int n = 0; n < 4; ++n) {
      const int col = bn + wc + n * 16 + lo;
      float bv = 0.f;
      if constexpr (HAS_BIAS) bv = bias[col];
      #pragma unroll
      for (int r = 0; r < 4; ++r) {
        const float v = acc[m][n][r] + bv;
        const long off = (long)blockIdx.z * sC + (long)(row0 + r) * N + col;
        if constexpr (F32OUT) ((float*)Cv)[off] = v;
        else ((_Float16*)Cv)[off] = (_Float16)v;
      }
    }
  }
}

// ---------------- local-branch repack: ql/kl -> Aq/Ak [h][256][512] ----------------
__global__ void repack_kernel(const _Float16* __restrict__ ql, const _Float16* __restrict__ kl,
                              _Float16* __restrict__ Aq, _Float16* __restrict__ Ak) {
  const _Float16* src = blockIdx.y ? kl : ql;
  _Float16* dst = blockIdx.y ? Ak : Aq;
  const int u = blockIdx.x * 256 + threadIdx.x;  // (h*256+q)*64 + c*8 + dseg
  const int dseg = u & 7, c = (u >> 3) & 7, q = (u >> 6) & 255, h = u >> 14;
  const long soff = (long)(h * 128 + c * 16 + (q >> 4)) * 1024 + (q & 15) * 64 + dseg * 8;
  *(h8*)&dst[(long)u * 8] = *(const h8*)&src[soff];
}

// ---------------- V column sums per head ----------------
__global__ void vsum_kernel(const _Float16* __restrict__ vl,
                            float* __restrict__ Vall, float* __restrict__ Vtail) {
  const int hh = blockIdx.x;
  const int d = threadIdx.x & 63, g = threadIdx.x >> 6;
  float sall = 0.f, shead = 0.f;
  for (int i = 0; i < 32; ++i) {
    const int ro = g * 32 + i;  // 0..127
    const _Float16* base = vl + (long)(hh * 128 + ro) * 1024 + d;
    #pragma unroll
    for (int j = 0; j < 16; ++j) {
      const float v = (float)base[j * 64];
      sall += v;
      if (ro < 16) shead += v;
    }
  }
  __shared__ float sA[4][64], sH[4][64];
  sA[g][d] = sall; sH[g][d] = shead;
  __syncthreads();
  if (g == 0) {
    const float a = sA[0][d] + sA[1][d] + sA[2][d] + sA[3][d];
    const float hsum = sH[0][d] + sH[1][d] + sH[2][d] + sH[3][d];
    Vall[hh * 64 + d] = a;
    Vtail[hh * 64 + d] = a - hsum;
  }
}

// ---------------- global branch: causal flash attention ----------------
__global__ __launch_bounds__(256) void flash_kernel(
    const _Float16* __restrict__ Q, const _Float16* __restrict__ Km,
    const _Float16* __restrict__ Vt, const int* __restrict__ gmask,
    _Float16* __restrict__ ctx) {
  const int qt = gridDim.x - 1 - blockIdx.x;   // heavy tiles first
  const int h = blockIdx.y;
  const int tid = threadIdx.x;
  const int w = tid >> 6, l = tid & 63;
  const int lo = l & 15, hi = l >> 4;
  __shared__ alignas(16) _Float16 Ks[64 * 64];
  __shared__ alignas(16) _Float16 Vs[64 * 64];   // [d][k] swizzled
  __shared__ alignas(16) _Float16 Ps[4][16 * 64];

  const f4 zero = {0.f, 0.f, 0.f, 0.f};
  const int qrow = qt * 64 + w * 16 + lo;
  h8 qf[2];
  #pragma unroll
  for (int kk = 0; kk < 2; ++kk)
    qf[kk] = *(const h8*)&Q[(long)qrow * EMB + h * DH + kk * 32 + hi * 8];

  f4 o[4];
  float mr[4], lr[4];
  #pragma unroll
  for (int r = 0; r < 4; ++r) { o[r] = zero; mr[r] = -1e30f; lr[r] = 0.f; }

  const int srow = tid >> 3, ssp = tid & 7;

  for (int kt = 0; kt <= qt; ++kt) {
    __syncthreads();
    #pragma unroll
    for (int i = 0; i < 2; ++i) {
      const int row = srow + i * 32;
      const h8 kv = *(const h8*)&Km[(long)(kt * 64 + row) * EMB + h * DH + ssp * 8];
      *(h8*)&Ks[row * 64 + ((ssp ^ (row & 7)) * 8)] = kv;
      const h8 vv = *(const h8*)&Vt[(long)(h * DH + row) * S_LEN + kt * 64 + ssp * 8];
      *(h8*)&Vs[row * 64 + ((ssp ^ (row & 7)) * 8)] = vv;
    }
    __syncthreads();

    f4 s[4];
    #pragma unroll
    for (int n = 0; n < 4; ++n) s[n] = zero;
    #pragma unroll
    for (int kk = 0; kk < 2; ++kk)
      #pragma unroll
      for (int n = 0; n < 4; ++n) {
        const int r = n * 16 + lo;
        const h8 b = *(const h8*)&Ks[r * 64 + (((kk * 4 + hi) ^ (r & 7)) * 8)];
        s[n] = mfma16(qf[kk], b, s[n]);
      }

    float sv[4][4];
    float tmax[4] = {-1e30f, -1e30f, -1e30f, -1e30f};
    const bool diag = (kt == qt);
    #pragma unroll
    for (int n = 0; n < 4; ++n) {
      const int key = n * 16 + lo;
      #pragma unroll
      for (int r = 0; r < 4; ++r) {
        float v = s[n][r] * 0.125f;
        if (diag && key > (w * 16 + hi * 4 + r)) v = -1e30f;
        sv[n][r] = v;
        tmax[r] = fmaxf(tmax[r], v);
      }
    }
    float cr[4];
    #pragma unroll
    for (int r = 0; r < 4; ++r) {
      float t = tmax[r];
      t = fmaxf(t, __shfl_xor(t, 1));
      t = fmaxf(t, __shfl_xor(t, 2));
      t = fmaxf(t, __shfl_xor(t, 4));
      t = fmaxf(t, __shfl_xor(t, 8));
      const float mn = fmaxf(mr[r], t);
      cr[r] = __expf(mr[r] - mn);
      mr[r] = mn;
    }
    float psum[4] = {0.f, 0.f, 0.f, 0.f};
    #pragma unroll
    for (int n = 0; n < 4; ++n) {
      const int col = n * 16 + lo;
      const int cseg = col >> 3, cj = col & 7;
      #pragma unroll
      for (int r = 0; r < 4; ++r) {
        const float p = __expf(sv[n][r] - mr[r]);
        psum[r] += p;
        const int row = hi * 4 + r;
        Ps[w][row * 64 + ((cseg ^ (row & 7)) * 8) + cj] = (_Float16)p;
      }
    }
    #pragma unroll
    for (int r = 0; r < 4; ++r) {
      float t = psum[r];
      t += __shfl_xor(t, 1);
      t += __shfl_xor(t, 2);
      t += __shfl_xor(t, 4);
      t += __shfl_xor(t, 8);
      lr[r] = lr[r] * cr[r] + t;
    }
    #pragma unroll
    for (int nd = 0; nd < 4; ++nd)
      #pragma unroll
      for (int r = 0; r < 4; ++r) o[nd][r] *= cr[r];
    #pragma unroll
    for (int kk = 0; kk < 2; ++kk) {
      const h8 pa = *(const h8*)&Ps[w][lo * 64 + (((kk * 4 + hi) ^ (lo & 7)) * 8)];
      #pragma unroll
      for (int nd = 0; nd < 4; ++nd) {
        const int r = nd * 16 + lo;
        const h8 vb = *(const h8*)&Vs[r * 64 + (((kk * 4 + hi) ^ (r & 7)) * 8)];
        o[nd] = mfma16(pa, vb, o[nd]);
      }
    }
  }

  #pragma unroll
  for (int r = 0; r < 4; ++r) {
    const int sg = qt * 64 + w * 16 + hi * 4 + r;
    if (gmask[sg] == 1) {
      const float inv = 1.f / lr[r];
      #pragma unroll
      for (int nd = 0; nd < 4; ++nd)
        ctx[(long)sg * EMB + h * DH + nd * 16 + lo] = (_Float16)(o[nd][r] * inv);
    }
  }
}

// ---------------- local branch softmax + weighted V (rows q<256, gmask==0) ----------------
__global__ void local2_kernel(const float* __restrict__ P, const _Float16* __restrict__ vl,
                              const float* __restrict__ Vtail, const int* __restrict__ gmask,
                              _Float16* __restrict__ ctx) {
  const int q = blockIdx.x, hh = blockIdx.y;
  if (gmask[q] == 1) return;
  const int l = threadIdx.x;  // 64
  __shared__ float wgt[256];
  const float* Pr = P + ((long)hh * 256 + q) * 256;
  float sv[4];
  bool valid[4];
  float M = -1e30f;
  #pragma unroll
  for (int i = 0; i < 4; ++i) {
    const int k = l + i * 64;
    valid[i] = (k <= q);
    sv[i] = valid[i] ? Pr[k] * 0.015625f : -1e30f;   // (1/8 mean)*(1/8 scale)
    M = fmaxf(M, sv[i]);
  }
  M = fmaxf(M, __shfl_xor(M, 1));
  M = fmaxf(M, __shfl_xor(M, 2));
  M = fmaxf(M, __shfl_xor(M, 4));
  M = fmaxf(M, __shfl_xor(M, 8));
  M = fmaxf(M, __shfl_xor(M, 16));
  M = fmaxf(M, __shfl_xor(M, 32));
  M = fmaxf(M, 0.f);   // 1792 zero-pad entries participate
  float ps = 0.f;
  #pragma unroll
  for (int i = 0; i < 4; ++i) {
    const float e = valid[i] ? __expf(sv[i] - M) : 0.f;
    wgt[l + i * 64] = e;
    ps += e;
  }
  ps += __shfl_xor(ps, 1);
  ps += __shfl_xor(ps, 2);
  ps += __shfl_xor(ps, 4);
  ps += __shfl_xor(ps, 8);
  ps += __shfl_xor(ps, 16);
  ps += __shfl_xor(ps, 32);
  const float em = __expf(-M);
  const float denom = ps + 1792.f * em;
  __syncthreads();
  const int d = l;
  float acc = em * Vtail[hh * 64 + d];
  const _Float16* vb = vl + (long)hh * 128 * 1024 + d;
  for (int k = 0; k <= q; ++k)
    acc += wgt[k] * (float)vb[(long)(k >> 4) * 1024 + (k & 15) * 64];
  ctx[(long)q * EMB + hh * DH + d] = (_Float16)(acc / denom);
}

// rows q>=256, gmask==0: uniform average of all vloc
__global__ void ftail_kernel(const float* __restrict__ Vall, const int* __restrict__ gmask,
                             _Float16* __restrict__ ctx) {
  const int gid = blockIdx.x * 256 + threadIdx.x;  // 1792*1024
  const int s = 256 + (gid >> 10), e = gid & 1023;
  if (gmask[s] == 0)
    ctx[(long)s * EMB + e] = (_Float16)(Vall[e] * (1.f / 2048.f));
}

// ---------------- launcher ----------------
extern "C" void kernel_launch(void* const* d_in, const int* in_sizes, int n_in,
                              void* d_out, int out_size, void* d_ws, size_t ws_size,
                              hipStream_t stream) {
  const float* x = (const float*)d_in[0];
  const int* gmask = (const int*)d_in[1];
  const float* Wlq = (const float*)d_in[2];
  const float* Wlk = (const float*)d_in[3];
  const float* Wlv = (const float*)d_in[4];
  const float* Wq = (const float*)d_in[5];
  const float* Wk = (const float*)d_in[6];
  const float* Wv = (const float*)d_in[7];
  const float* Wp = (const float*)d_in[8];
  const float* bp = (const float*)d_in[9];
  float* out = (float*)d_out;

  char* ws = (char*)d_ws;
  // region reuse schedule (stream-ordered, no overlap of live ranges):
  _Float16* xh = (_Float16*)(ws);                    // [0,4MB)  -> later vgT
  _Float16* Wtb = (_Float16*)(ws + (4u << 20));      // [4,18MB) -> slabs0-5 later Aq/Ak/P
  _Float16* proj = (_Float16*)(ws + (18u << 20));    // [18,42MB)
  _Float16* ql = proj;                               // 18MB -> later ctx
  _Float16* kl = (_Float16*)(ws + (22u << 20));      // 22MB -> later Vall/Vtail
  _Float16* vl = (_Float16*)(ws + (26u << 20));
  _Float16* qg = (_Float16*)(ws + (30u << 20));
  _Float16* kg = (_Float16*)(ws + (34u << 20));
  _Float16* vg = (_Float16*)(ws + (38u << 20));
  _Float16* Aq = (_Float16*)(ws + (4u << 20));
  _Float16* Ak = (_Float16*)(ws + (8u << 20));
  float* P = (float*)(ws + (12u << 20));
  _Float16* Wpt = (_Float16*)(ws + (16u << 20));     // Wtb slab 6 (kept live)
  _Float16* vgT = (_Float16*)(ws);
  _Float16* ctx = (_Float16*)(ws + (18u << 20));
  float* Vall = (float*)(ws + (22u << 20));
  float* Vtail = (float*)(ws + (22u << 20) + 4096);

  cvtx_kernel<<<2048, 256, 0, stream>>>(x, xh);
  twcvt_kernel<<<dim3(32, 32, 7), 256, 0, stream>>>(Wlq, Wlk, Wlv, Wq, Wk, Wv, Wp, Wtb);
  gemm_kernel<false, false><<<dim3(16, 8, 6), 256, 0, stream>>>(
      xh, Wtb, proj, nullptr, 2048, 1024, 1024, 0L, 1048576L, 2097152L);
  repack_kernel<<<dim3(1024, 2), 256, 0, stream>>>(ql, kl, Aq, Ak);
  gemm_kernel<true, false><<<dim3(2, 2, 16), 256, 0, stream>>>(
      Aq, Ak, P, nullptr, 256, 256, 512, 131072L, 131072L, 65536L);
  vsum_kernel<<<16, 256, 0, stream>>>(vl, Vall, Vtail);
  tvg_kernel<<<dim3(64, 32), 256, 0, stream>>>(vg, vgT);
  flash_kernel<<<dim3(32, 16), 256, 0, stream>>>(qg, kg, vgT, gmask, ctx);
  local2_kernel<<<dim3(256, 16), 64, 0, stream>>>(P, vl, Vtail, gmask, ctx);
  ftail_kernel<<<7168, 256, 0, stream>>>(Vall, gmask, ctx);
  gemm_kernel<true, true><<<dim3(16, 8, 1), 256, 0, stream>>>(
      ctx, Wpt, out, bp, 2048, 1024, 1024, 0L, 0L, 0L);
}